// Round 4
// baseline (550.205 us; speedup 1.0000x reference)
//
#include <hip/hip_runtime.h>
#include <hip/hip_bf16.h>
#include <cstddef>

#define L_SEQ 2048
#define CDIM  1024
#define NH    16
#define HD    64

typedef __attribute__((ext_vector_type(8))) short bf16x8;
typedef __attribute__((ext_vector_type(4))) float f32x4;

typedef __attribute__((address_space(3))) unsigned int lds_uint;
typedef const __attribute__((address_space(1))) unsigned int glob_uint;

__device__ __forceinline__ void gll16(const void* g, void* l) {
    __builtin_amdgcn_global_load_lds((glob_uint*)g, (lds_uint*)l, 16, 0, 0);
}
__device__ __forceinline__ short f2bf(float f) {
    __hip_bfloat16 h = __float2bfloat16(f);
    return *reinterpret_cast<short*>(&h);
}
__device__ __forceinline__ float bf2f(short s) {
    __hip_bfloat16 h = *reinterpret_cast<__hip_bfloat16*>(&s);
    return __bfloat162float(h);
}

// ======================================================================
// cast fp32 -> bf16, 8 elems/thread
// ======================================================================
__global__ __launch_bounds__(256) void cast_bf16(
    const float* __restrict__ src, short* __restrict__ dst, int n8)
{
    int t = blockIdx.x * 256 + threadIdx.x;
    if (t >= n8) return;
    float4 a = ((const float4*)src)[t * 2];
    float4 b = ((const float4*)src)[t * 2 + 1];
    short tmp[8] = { f2bf(a.x), f2bf(a.y), f2bf(a.z), f2bf(a.w),
                     f2bf(b.x), f2bf(b.y), f2bf(b.z), f2bf(b.w) };
    ((uint4*)dst)[t] = *(uint4*)tmp;
}

// ======================================================================
// transpose-cast: W (K x N) fp32 -> WT (N x K) bf16.  64x64 LDS tile.
// ======================================================================
__global__ __launch_bounds__(256) void transpose_cast(
    const float* __restrict__ W, short* __restrict__ WT, int K, int N)
{
    __shared__ float t[64][65];
    const int n0 = blockIdx.x * 64, k0 = blockIdx.y * 64;
    const int tid = threadIdx.x;
#pragma unroll
    for (int j = 0; j < 4; ++j) {
        int e = tid + j * 256;
        int r = e >> 4, c4 = e & 15;
        *(float4*)&t[r][c4 * 4] = *(const float4*)(W + (size_t)(k0 + r) * N + n0 + c4 * 4);
    }
    __syncthreads();
#pragma unroll
    for (int j = 0; j < 2; ++j) {
        int e = tid + j * 256;
        int nr = e >> 3, c8 = (e & 7) * 8;
        short tmp[8];
#pragma unroll
        for (int i = 0; i < 8; ++i) tmp[i] = f2bf(t[c8 + i][nr]);
        *(uint4*)(WT + (size_t)(n0 + nr) * K + k0 + c8) = *(uint4*)tmp;
    }
}

// ======================================================================
// QKV GEMM bf16 MFMA + fused RoPE (Q pre-scaled 1/8) + scatter.
// V: scalar scatter to (B,H,D,L)  [round-2 proven path].
// ======================================================================
__global__ __launch_bounds__(256) void gemm_qkv(
    const short* __restrict__ A, const short* __restrict__ BT,
    const float* __restrict__ freqs,
    short* __restrict__ Qb, short* __restrict__ Kb, short* __restrict__ Vt)
{
    __shared__ short As[128 * 32];
    __shared__ short Bs[128 * 32];
    const int tid = threadIdx.x;
    const int w = tid >> 6, lane = tid & 63;
    const int m0 = blockIdx.y * 128, n0 = blockIdx.x * 128;
    const int K = CDIM;
    const int rsub = lane >> 2;
    const int kcol = (lane & 3) * 8;
    f32x4 acc[4][4] = {};

    for (int k0 = 0; k0 < K; k0 += 32) {
#pragma unroll
        for (int seg = 0; seg < 2; ++seg) {
            int r = w * 32 + seg * 16 + rsub;
            gll16(A  + (size_t)(m0 + r) * K + k0 + kcol, &As[(w * 32 + seg * 16) * 32]);
            gll16(BT + (size_t)(n0 + r) * K + k0 + kcol, &Bs[(w * 32 + seg * 16) * 32]);
        }
        __syncthreads();
        bf16x8 af[4], bfr[4];
#pragma unroll
        for (int i = 0; i < 4; ++i) {
            af[i]  = *(const bf16x8*)&As[((w >> 1) * 64 + i * 16 + (lane & 15)) * 32 + (lane >> 4) * 8];
            bfr[i] = *(const bf16x8*)&Bs[((w & 1)  * 64 + i * 16 + (lane & 15)) * 32 + (lane >> 4) * 8];
        }
#pragma unroll
        for (int i = 0; i < 4; ++i)
#pragma unroll
            for (int j = 0; j < 4; ++j)
                acc[i][j] = __builtin_amdgcn_mfma_f32_16x16x32_bf16(af[i], bfr[j], acc[i][j], 0, 0, 0);
        __syncthreads();
    }

    const int region = n0 >> 10;          // 0=Q 1=K 2=V (block-uniform)
    const int wr = w >> 1, wc = w & 1;
    const int crow = (lane >> 4) * 4, ccol = lane & 15;

    if (region == 2) {
        // ---- V: scalar scatter (round-2 proven) ----
#pragma unroll
        for (int i = 0; i < 4; ++i)
#pragma unroll
            for (int j = 0; j < 4; ++j) {
                int cc = (n0 & 1023) + wc * 64 + j * 16 + ccol;
                int h = cc >> 6, d = cc & 63;
#pragma unroll
                for (int r = 0; r < 4; ++r) {
                    int m = m0 + wr * 64 + i * 16 + crow + r;
                    int bb = m >> 11, l = m & (L_SEQ - 1);
                    Vt[((size_t)(bb * NH + h) * HD + d) * L_SEQ + l] = f2bf(acc[i][j][r]);
                }
            }
    } else {
        // ---- Q/K: fused RoPE on fp32 acc (+1/8 scale for Q) ----
        const float qs = (region == 0) ? 0.125f : 1.0f;
        short* dst = (region == 0) ? Qb : Kb;
#pragma unroll
        for (int i = 0; i < 4; ++i)
#pragma unroll
            for (int r = 0; r < 4; ++r) {
                int m = m0 + wr * 64 + i * 16 + crow + r;
                int bb = m >> 11, l = m & (L_SEQ - 1);
#pragma unroll
                for (int j = 0; j < 4; ++j) {
                    int cc = (n0 & 1023) + wc * 64 + j * 16 + ccol;
                    int h = cc >> 6, d = cc & 63;
                    float v  = acc[i][j][r];
                    float vp = __shfl_xor(v, 1, 64);          // partner d^1 value
                    float fo = freqs[l * HD + d];
                    float fp = __shfl_xor(fo, 1, 64);         // partner's freq
                    float o = (d & 1) ? (v * fp + vp * fo) : (v * fo - vp * fp);
                    dst[((size_t)(bb * NH + h) * L_SEQ + l) * HD + d] = f2bf(o * qs);
                }
            }
    }
}

// ======================================================================
// Flash attention, bf16 MFMA, register-pipelined K/V/bias prefetch,
// Q in registers, defer-rescale (THR=0, bit-exact).
// grid (L/64, NH, B), 256 thr = 4 waves; wave w owns q rows w*16..+16.
// ======================================================================
__global__ __launch_bounds__(256) void attn_mfma(
    const short* __restrict__ Qb, const short* __restrict__ Kb,
    const short* __restrict__ Vt, const float* __restrict__ bias,
    short* __restrict__ Ab)
{
    __shared__ short Ks[64][72];
    __shared__ short Vs[64][72];     // V^T tile: [d][k]
    __shared__ short Ps[4][16][72];  // per-wave P
    const int tid = threadIdx.x, w = tid >> 6, lane = tid & 63;
    const int q0 = blockIdx.x * 64, h = blockIdx.y, b = blockIdx.z;
    const int g = lane >> 4, c = lane & 15;
    const short* Qp = Qb + (size_t)((b * NH + h) * L_SEQ + q0) * HD;
    const short* Kp = Kb + (size_t)((b * NH + h) * L_SEQ) * HD;
    const short* Vp = Vt + (size_t)((b * NH + h) * HD) * L_SEQ;
    const float* bp = bias + (size_t)h * L_SEQ * L_SEQ + (size_t)q0 * L_SEQ;

    // Q fragments straight to registers (row = w*16+c, k-slices g*8, 32+g*8)
    bf16x8 aq0 = *(const bf16x8*)(Qp + (w * 16 + c) * HD + g * 8);
    bf16x8 aq1 = *(const bf16x8*)(Qp + (w * 16 + c) * HD + 32 + g * 8);

    // cooperative staging geometry
    const int srow = tid >> 3;           // 0..31
    const int scol = (tid & 7) * 8;

    float m_run[4], l_run[4];
    f32x4 oacc[4] = {};
#pragma unroll
    for (int r = 0; r < 4; ++r) { m_run[r] = -1e30f; l_run[r] = 0.f; }

    // prologue: prefetch tile 0 into registers
    uint4 kr0 = *(const uint4*)(Kp + (size_t)srow * HD + scol);
    uint4 kr1 = *(const uint4*)(Kp + (size_t)(srow + 32) * HD + scol);
    uint4 vr0 = *(const uint4*)(Vp + (size_t)srow * L_SEQ + scol);
    uint4 vr1 = *(const uint4*)(Vp + (size_t)(srow + 32) * L_SEQ + scol);
    float br[4][4];
#pragma unroll
    for (int j = 0; j < 4; ++j)
#pragma unroll
        for (int r = 0; r < 4; ++r)
            br[j][r] = bp[(size_t)(w * 16 + g * 4 + r) * L_SEQ + j * 16 + c];

    for (int kt = 0; kt < L_SEQ / 64; ++kt) {
        __syncthreads();                 // prev-iter LDS reads done
        *(uint4*)&Ks[srow][scol]      = kr0;
        *(uint4*)&Ks[srow + 32][scol] = kr1;
        *(uint4*)&Vs[srow][scol]      = vr0;
        *(uint4*)&Vs[srow + 32][scol] = vr1;
        f32x4 sacc[4];
#pragma unroll
        for (int j = 0; j < 4; ++j)
#pragma unroll
            for (int r = 0; r < 4; ++r) sacc[j][r] = br[j][r];
        __syncthreads();                 // LDS ready

        // prefetch tile kt+1 (latency hides under this iteration's compute)
        if (kt + 1 < L_SEQ / 64) {
            const int kn = (kt + 1) * 64;
            kr0 = *(const uint4*)(Kp + (size_t)(kn + srow) * HD + scol);
            kr1 = *(const uint4*)(Kp + (size_t)(kn + srow + 32) * HD + scol);
            vr0 = *(const uint4*)(Vp + (size_t)srow * L_SEQ + kn + scol);
            vr1 = *(const uint4*)(Vp + (size_t)(srow + 32) * L_SEQ + kn + scol);
#pragma unroll
            for (int j = 0; j < 4; ++j)
#pragma unroll
                for (int r = 0; r < 4; ++r)
                    br[j][r] = bp[(size_t)(w * 16 + g * 4 + r) * L_SEQ + kn + j * 16 + c];
        }

        // S = Q K^T + bias (scale folded into Q)
#pragma unroll
        for (int j = 0; j < 4; ++j) {
            bf16x8 bk0 = *(const bf16x8*)&Ks[j * 16 + c][g * 8];
            sacc[j] = __builtin_amdgcn_mfma_f32_16x16x32_bf16(aq0, bk0, sacc[j], 0, 0, 0);
            bf16x8 bk1 = *(const bf16x8*)&Ks[j * 16 + c][32 + g * 8];
            sacc[j] = __builtin_amdgcn_mfma_f32_16x16x32_bf16(aq1, bk1, sacc[j], 0, 0, 0);
        }

        // online softmax with defer-rescale (THR=0 -> bit-exact)
        float tmv[4];
#pragma unroll
        for (int r = 0; r < 4; ++r) {
            float t0 = fmaxf(fmaxf(sacc[0][r], sacc[1][r]), fmaxf(sacc[2][r], sacc[3][r]));
#pragma unroll
            for (int off = 1; off < 16; off <<= 1)
                t0 = fmaxf(t0, __shfl_xor(t0, off, 64));
            tmv[r] = t0;
        }
        int grow = 0;
#pragma unroll
        for (int r = 0; r < 4; ++r) grow |= (tmv[r] > m_run[r]) ? 1 : 0;
        if (__any(grow)) {
#pragma unroll
            for (int r = 0; r < 4; ++r) {
                float mn = fmaxf(m_run[r], tmv[r]);
                float fct = __expf(m_run[r] - mn);
                l_run[r] *= fct;
                m_run[r] = mn;
#pragma unroll
                for (int di = 0; di < 4; ++di) oacc[di][r] *= fct;
            }
        }
#pragma unroll
        for (int r = 0; r < 4; ++r) {
            float acc = 0.f;
#pragma unroll
            for (int j = 0; j < 4; ++j) {
                sacc[j][r] = __expf(sacc[j][r] - m_run[r]);
                acc += sacc[j][r];
            }
#pragma unroll
            for (int off = 1; off < 16; off <<= 1) acc += __shfl_xor(acc, off, 64);
            l_run[r] += acc;
        }

        // stage P (bf16) into per-wave LDS
#pragma unroll
        for (int j = 0; j < 4; ++j)
#pragma unroll
            for (int r = 0; r < 4; ++r)
                Ps[w][g * 4 + r][j * 16 + c] = f2bf(sacc[j][r]);
        asm volatile("" ::: "memory");   // same-wave LDS write->read ordering

        // O += P V
#pragma unroll
        for (int kb = 0; kb < 2; ++kb) {
            bf16x8 pa = *(const bf16x8*)&Ps[w][c][kb * 32 + g * 8];
#pragma unroll
            for (int di = 0; di < 4; ++di) {
                bf16x8 vb = *(const bf16x8*)&Vs[di * 16 + c][kb * 32 + g * 8];
                oacc[di] = __builtin_amdgcn_mfma_f32_16x16x32_bf16(pa, vb, oacc[di], 0, 0, 0);
            }
        }
    }

    // epilogue: normalize, write bf16 to (B*L, C)
#pragma unroll
    for (int di = 0; di < 4; ++di)
#pragma unroll
        for (int r = 0; r < 4; ++r) {
            int m = b * L_SEQ + q0 + w * 16 + g * 4 + r;
            int col = h * HD + di * 16 + c;
            Ab[(size_t)m * CDIM + col] = f2bf(oacc[di][r] / l_run[r]);
        }
}

// ======================================================================
// proj GEMM bf16 MFMA: 128x64 tile (512 blocks, 2/CU), +bias, fp32 out
// ======================================================================
__global__ __launch_bounds__(256) void gemm_proj(
    const short* __restrict__ A, const short* __restrict__ BT,
    const float* __restrict__ bprj, float* __restrict__ out)
{
    __shared__ short As[128 * 32];
    __shared__ short Bs[64 * 32];
    const int tid = threadIdx.x;
    const int w = tid >> 6, lane = tid & 63;
    const int m0 = blockIdx.y * 128, n0 = blockIdx.x * 64;
    const int K = CDIM;
    const int rsub = lane >> 2;
    const int kcol = (lane & 3) * 8;
    f32x4 acc[4][2] = {};

    for (int k0 = 0; k0 < K; k0 += 32) {
#pragma unroll
        for (int seg = 0; seg < 2; ++seg) {
            int r = w * 32 + seg * 16 + rsub;
            gll16(A + (size_t)(m0 + r) * K + k0 + kcol, &As[(w * 32 + seg * 16) * 32]);
        }
        {
            int r = w * 16 + rsub;
            gll16(BT + (size_t)(n0 + r) * K + k0 + kcol, &Bs[(w * 16) * 32]);
        }
        __syncthreads();
        bf16x8 af[4], bfr[2];
#pragma unroll
        for (int i = 0; i < 4; ++i)
            af[i] = *(const bf16x8*)&As[((w >> 1) * 64 + i * 16 + (lane & 15)) * 32 + (lane >> 4) * 8];
#pragma unroll
        for (int j = 0; j < 2; ++j)
            bfr[j] = *(const bf16x8*)&Bs[((w & 1) * 32 + j * 16 + (lane & 15)) * 32 + (lane >> 4) * 8];
#pragma unroll
        for (int i = 0; i < 4; ++i)
#pragma unroll
            for (int j = 0; j < 2; ++j)
                acc[i][j] = __builtin_amdgcn_mfma_f32_16x16x32_bf16(af[i], bfr[j], acc[i][j], 0, 0, 0);
        __syncthreads();
    }

    const int wr = w >> 1, wc = w & 1;
    const int crow = (lane >> 4) * 4, ccol = lane & 15;
#pragma unroll
    for (int i = 0; i < 4; ++i)
#pragma unroll
        for (int j = 0; j < 2; ++j) {
            int n = n0 + wc * 32 + j * 16 + ccol;
            float bv = bprj[n];
#pragma unroll
            for (int r = 0; r < 4; ++r) {
                int m = m0 + wr * 64 + i * 16 + crow + r;
                out[(size_t)m * CDIM + n] = acc[i][j][r] + bv;
            }
        }
}

// ======================================================================
extern "C" void kernel_launch(void* const* d_in, const int* in_sizes, int n_in,
                              void* d_out, int out_size, void* d_ws, size_t ws_size,
                              hipStream_t stream) {
    const float* x     = (const float*)d_in[0];
    const float* freqs = (const float*)d_in[1];
    const float* bias  = (const float*)d_in[2];
    const float* w_qkv = (const float*)d_in[3];
    const float* w_prj = (const float*)d_in[4];
    const float* b_prj = (const float*)d_in[5];
    float* out = (float*)d_out;

    short* ws = (short*)d_ws;
    short* xb     = ws;                       // 4096*1024
    short* wqkvT  = xb + 4194304;             // 3072*1024
    short* wprojT = wqkvT + 3145728;          // 1024*1024
    short* Qb     = wprojT + 1048576;         // (B,H,L,D)
    short* Kb     = Qb + 4194304;
    short* Vt     = Kb + 4194304;             // (B,H,D,L)
    short* Ab     = Vt + 4194304;             // (B*L, C)

    cast_bf16<<<2048, 256, 0, stream>>>(x, xb, 524288);
    transpose_cast<<<dim3(48, 16), 256, 0, stream>>>(w_qkv, wqkvT, CDIM, 3 * CDIM);
    transpose_cast<<<dim3(16, 16), 256, 0, stream>>>(w_prj, wprojT, CDIM, CDIM);
    gemm_qkv<<<dim3(24, 32), 256, 0, stream>>>(xb, wqkvT, freqs, Qb, Kb, Vt);
    attn_mfma<<<dim3(32, NH, 2), 256, 0, stream>>>(Qb, Kb, Vt, bias, Ab);
    gemm_proj<<<dim3(16, 32), 256, 0, stream>>>(Ab, wprojT, b_prj, out);
}